// Round 6
// baseline (311.242 us; speedup 1.0000x reference)
//
#include <hip/hip_runtime.h>
#include <hip/hip_bf16.h>

typedef float f32x4 __attribute__((ext_vector_type(4)));
typedef short bf16x8 __attribute__((ext_vector_type(8)));

#define ZT 16              // samples per workgroup
#define TL_RING 16384      // ring size in ushorts: 128 cols x 128 u (32.8 KB)
#define YL_BUF 448         // 16 z * max padded span 28

// PATHS enumerated l1-major, l2, lo with |l1-l2|<=lo<=l1+l2
constexpr int cL1[15]  = {0,0,0,1,1,1,1,1,1,2,2,2,2,2,2};
constexpr int cL2[15]  = {0,1,2,0,1,1,1,2,2,0,1,1,2,2,2};
constexpr int cLO[15]  = {0,1,2,1,0,1,2,1,2,2,1,2,0,1,2};
constexpr int cCSZ[15] = {1,9,25,9,9,27,45,45,75,25,45,75,25,75,125};
constexpr int cCOFF[15]= {0,1,10,35,44,53,80,125,170,245,270,315,390,415,490}; // total 615
constexpr int cO1[3] = {0,128,512};  // x1 / out irrep block offsets (floats)
constexpr int cO2[3] = {0,1,4};      // x2 irrep block offsets

// Path sequence GROUPED BY l1 (x1 block regs reused within group; loaded at
// group starts S=0,3,9) + ring offsets (cols). Consecutive regions disjoint:
// [0,80)[80,128)[0,16)[48,128)[0,48)[112,128)[0,80)[80,128)[0,48)[48,128)
// [0,48)[48,128)[0,16)[80,128)[0,80).
constexpr int cSEQ [15] = {2,1,0, 6,3,4,8,5,7, 9,10,11,12,13,14};
constexpr int cROFF[15] = {0,80,0, 48,0,112,0,80,0, 48,0,48,0,80,0};

struct CP { const float* p[15]; };

__device__ __forceinline__ ushort f2bf(float f) {
    union { __hip_bfloat16 h; ushort u; } c;
    c.h = __float2bfloat16(f);
    return c.u;
}

// ---- prep kernel: Wb[p][w][u] = bf16(ws[p][u][0][w]) (transpose + convert) ----
__global__ void prep_w(const float* __restrict__ ws, ushort* __restrict__ wb) {
    __shared__ float lds[64 * 132];
    const int p = blockIdx.x;
    const int tid = threadIdx.x;
    const float* src = ws + (size_t)p * 16384;
    ushort* dst = wb + (size_t)p * 16384;
    for (int half = 0; half < 2; ++half) {
        for (int i = tid; i < 8192; i += 256) {          // load 64 u-rows, coalesced
            int u = i >> 7, w = i & 127;
            lds[u * 132 + w] = src[(half * 64 + u) * 128 + w];
        }
        __syncthreads();
        for (int i = tid; i < 8192; i += 256) {          // store transposed, coalesced
            int w = i >> 6, u = i & 63;
            dst[w * 128 + half * 64 + u] = f2bf(lds[u * 132 + w]);
        }
        __syncthreads();
    }
}

// ---- y[z,i,k] = sum_j c[i,j,k] * x2[z, O2[l2]+j], padded per-z stride ----
template<int P>
__device__ __forceinline__ void compute_y(int tid, const float* __restrict__ cl,
                                          const float* __restrict__ x2l,
                                          float* __restrict__ ybuf) {
    constexpr int l2 = cL2[P], lo = cLO[P];
    constexpr int d1 = 2*cL1[P]+1, d2 = 2*l2+1, dO = 2*lo+1;
    constexpr int span = d1 * dO;
    constexpr int span_pad = (span + 3) & ~3;
    constexpr int ny = ZT * span_pad;
    for (int idx = tid; idx < ny; idx += 256) {
        const int z = idx / span_pad, rem = idx - z * span_pad;
        float s = 0.f;
        if (rem < span) {
            const int i = rem / dO, k = rem - i * dO;
            #pragma unroll
            for (int j = 0; j < d2; ++j)
                s += cl[cCOFF[P] + (i*d2 + j)*dO + k] * x2l[z*9 + cO2[l2] + j];
        }
        ybuf[idx] = s;   // pad slots get 0; never consumed
    }
}

// ---- load current l1-block of x1 into regs (thread: u-pair 2*lane, z=4*wv+r) ----
template<int L1>
__device__ __forceinline__ void load_x1(const float* __restrict__ x1, int z0,
                                        int wv, int lane, float (&x1c)[4][2][5]) {
    #pragma unroll
    for (int r = 0; r < 4; ++r) {
        const float* b = x1 + (size_t)(z0 + wv*4 + r) * 1152;
        if constexpr (L1 == 0) {
            const float2 t = *reinterpret_cast<const float2*>(b + 2*lane);
            x1c[r][0][0] = t.x; x1c[r][1][0] = t.y;
        } else if constexpr (L1 == 1) {
            float f6[6];
            #pragma unroll
            for (int j = 0; j < 3; ++j) {
                const float2 t = *reinterpret_cast<const float2*>(b + 128 + 6*lane + 2*j);
                f6[2*j] = t.x; f6[2*j + 1] = t.y;
            }
            #pragma unroll
            for (int i = 0; i < 3; ++i) { x1c[r][0][i] = f6[i]; x1c[r][1][i] = f6[3+i]; }
        } else {
            float f10[10];
            #pragma unroll
            for (int j = 0; j < 5; ++j) {
                const float2 t = *reinterpret_cast<const float2*>(b + 512 + 10*lane + 2*j);
                f10[2*j] = t.x; f10[2*j + 1] = t.y;
            }
            #pragma unroll
            for (int i = 0; i < 5; ++i) { x1c[r][0][i] = f10[i]; x1c[r][1][i] = f10[5+i]; }
        }
    }
}

// ---- one sequence step: [x1 group load] -> T -> W-prefetch -> y(next) -> barrier -> MFMA ----
template<int S>
__device__ __forceinline__ void path_iter(
    int tid, const float* __restrict__ x1, int z0,
    const ushort* __restrict__ Wb, const float* __restrict__ Wsrc, int use_prep,
    float (&x1c)[4][2][5],
    float* __restrict__ yl, ushort* __restrict__ Tl,
    const float* __restrict__ cl, const float* __restrict__ x2l,
    f32x4 (&A0)[1][2], f32x4 (&A1)[3][2], f32x4 (&A2)[5][2])
{
    constexpr int P = cSEQ[S];
    constexpr int l1 = cL1[P], lo = cLO[P];
    constexpr int d1 = 2*l1+1, dO = 2*lo+1;
    constexpr int span = d1 * dO;
    constexpr int span_pad = (span + 3) & ~3;
    const int lane = tid & 63, wv = tid >> 6;

    ushort* Tcur = Tl + cROFF[S] * 128;             // ring region (cols x 128 u)
    const float* ycur = yl + (S & 1) * YL_BUF;

    // --- refresh x1 block registers at l1-group starts ---
    if constexpr (S == 0 || cL1[cSEQ[S - 1]] != l1)
        load_x1<l1>(x1, z0, wv, lane, x1c);

    // --- T-phase: thread owns u-pair (2*lane, 2*lane+1), z in {4*wv..4*wv+3}.
    //     Stride 128 ushorts + XOR swizzle (col&7)<<3 (write/read same involution) ---
    {
        const int u0 = 2 * lane;
        #pragma unroll
        for (int r = 0; r < 4; ++r) {
            const int z = wv * 4 + r;
            f32x4 yv[span_pad / 4];
            #pragma unroll
            for (int j = 0; j < span_pad / 4; ++j)
                yv[j] = *reinterpret_cast<const f32x4*>(ycur + z * span_pad + 4 * j);
            #pragma unroll
            for (int k = 0; k < dO; ++k) {
                const int col = z * dO + k;
                float s0 = 0.f, s1 = 0.f;
                #pragma unroll
                for (int i = 0; i < d1; ++i) {
                    const int yi = i * dO + k;              // compile-time after unroll
                    const float yf = yv[yi >> 2][yi & 3];
                    s0 += x1c[r][0][i] * yf;
                    s1 += x1c[r][1][i] * yf;
                }
                union { uint u32; ushort h[2]; } pk;
                pk.h[0] = f2bf(s0);
                pk.h[1] = f2bf(s1);
                const uint idx = (uint)(col * 128 + u0) ^ (uint)((col & 7) << 3);
                *reinterpret_cast<uint*>(Tcur + idx) = pk.u32;
            }
        }
    }

    // --- prefetch weight fragments (MFMA B-operand: k=u, col=w). After T-phase
    //     to keep peak live-set low; L2-resident, latency hides under y+barrier ---
    bf16x8 aP[2][4];
    if (use_prep) {
        const ushort* wp = Wb + P * 16384;
        #pragma unroll
        for (int nt = 0; nt < 2; ++nt)
        #pragma unroll
        for (int ks = 0; ks < 4; ++ks) {
            const int wrow = wv*32 + nt*16 + (lane & 15);
            const int k0   = ks*32 + ((lane >> 4) << 3);
            aP[nt][ks] = *reinterpret_cast<const bf16x8*>(wp + wrow*128 + k0);
        }
    } else {
        const float* wp = Wsrc + P * 16384;   // fallback: strided f32 reads of ws[p][u][0][w]
        #pragma unroll
        for (int nt = 0; nt < 2; ++nt)
        #pragma unroll
        for (int ks = 0; ks < 4; ++ks) {
            const int wrow = wv*32 + nt*16 + (lane & 15);
            const int k0   = ks*32 + ((lane >> 4) << 3);
            bf16x8 v;
            #pragma unroll
            for (int e = 0; e < 8; ++e) v[e] = (short)f2bf(wp[(k0 + e)*128 + wrow]);
            aP[nt][ks] = v;
        }
    }

    // --- overlap: compute next path's y into the other yl buffer ---
    if constexpr (S < 14)
        compute_y<cSEQ[S + 1]>(tid, cl, x2l, yl + ((S + 1) & 1) * YL_BUF);

    __syncthreads();   // T ready; ring adjacency guarantees no WAR with prev path

    // --- MFMA (swapped operands): D[w][zcol] with A=T (rows=zcol,k=u), B=W ---
    #pragma unroll
    for (int t = 0; t < dO; ++t) {
        #pragma unroll
        for (int ks = 0; ks < 4; ++ks) {
            const int col = t*16 + (lane & 15);
            const int k0  = ks*32 + ((lane >> 4) << 3);
            const uint idx = (uint)(col * 128 + k0) ^ (uint)((col & 7) << 3);
            const bf16x8 a = *reinterpret_cast<const bf16x8*>(Tcur + idx);
            if constexpr (lo == 0) {
                A0[t][0] = __builtin_amdgcn_mfma_f32_16x16x32_bf16(a, aP[0][ks], A0[t][0], 0,0,0);
                A0[t][1] = __builtin_amdgcn_mfma_f32_16x16x32_bf16(a, aP[1][ks], A0[t][1], 0,0,0);
            } else if constexpr (lo == 1) {
                A1[t][0] = __builtin_amdgcn_mfma_f32_16x16x32_bf16(a, aP[0][ks], A1[t][0], 0,0,0);
                A1[t][1] = __builtin_amdgcn_mfma_f32_16x16x32_bf16(a, aP[1][ks], A1[t][1], 0,0,0);
            } else {
                A2[t][0] = __builtin_amdgcn_mfma_f32_16x16x32_bf16(a, aP[0][ks], A2[t][0], 0,0,0);
                A2[t][1] = __builtin_amdgcn_mfma_f32_16x16x32_bf16(a, aP[1][ks], A2[t][1], 0,0,0);
            }
        }
    }
}

// ---- epilogue: stage acc (scaled) into LDS out-layout chunk of 4 z ----
// D layout: col(lane&15)->w, row((lane>>4)*4+r)->zcol. Stage write stride across
// the 16 m-lanes = dO -> 16 distinct banks -> conflict-free.
template<int LO, int NTILES>
__device__ __forceinline__ void stage_lo(const f32x4 (&A)[NTILES][2], float* __restrict__ stage,
                                         int c, int wv, int g, int m, float scale)
{
    constexpr int dO = 2*LO + 1;
    #pragma unroll
    for (int t = 0; t < NTILES; ++t)
    #pragma unroll
    for (int r = 0; r < 4; ++r) {
        const int zcol = t*16 + g*4 + r;
        const int z = zcol / dO, k = zcol - z*dO;
        if ((z >> 2) == c) {
            #pragma unroll
            for (int nt = 0; nt < 2; ++nt) {
                const int w = wv*32 + nt*16 + m;
                stage[(z & 3)*1152 + cO1[LO] + w*dO + k] = A[t][nt][r] * scale;
            }
        }
    }
}

__global__ __launch_bounds__(256, 3)
void tp_main(const float* __restrict__ x1, const float* __restrict__ x2,
             const float* __restrict__ wsrc, const ushort* __restrict__ wb,
             int use_prep, CP cp, float* __restrict__ out)
{
    __shared__ __align__(16) ushort Tl[TL_RING];      // 32.8 KB ring
    __shared__ __align__(16) float yl[2 * YL_BUF];    // 3.6 KB double-buffered y
    __shared__ float cl[615];
    __shared__ float x2l[ZT * 9];

    const int tid = threadIdx.x;
    const int z0 = blockIdx.x * ZT;
    const int lane = tid & 63, wv = tid >> 6;

    // preload all CG tensors and the x2 tile
    #pragma unroll
    for (int p = 0; p < 15; ++p)
        for (int i = tid; i < cCSZ[p]; i += 256) cl[cCOFF[p] + i] = cp.p[p][i];
    for (int i = tid; i < ZT * 9; i += 256) x2l[i] = x2[(size_t)z0 * 9 + i];

    float x1c[4][2][5];   // current l1-group x1 block (<=40 regs), loaded per group

    f32x4 A0[1][2], A1[3][2], A2[5][2];
    #pragma unroll
    for (int nt = 0; nt < 2; ++nt) {
        A0[0][nt] = (f32x4){0.f, 0.f, 0.f, 0.f};
        #pragma unroll
        for (int t = 0; t < 3; ++t) A1[t][nt] = (f32x4){0.f, 0.f, 0.f, 0.f};
        #pragma unroll
        for (int t = 0; t < 5; ++t) A2[t][nt] = (f32x4){0.f, 0.f, 0.f, 0.f};
    }

    __syncthreads();                           // cl / x2l ready
    compute_y<cSEQ[0]>(tid, cl, x2l, yl);      // prime y for first path into yl[0]
    __syncthreads();                           // y ready

    path_iter< 0>(tid, x1, z0, wb, wsrc, use_prep, x1c, yl, Tl, cl, x2l, A0, A1, A2);
    path_iter< 1>(tid, x1, z0, wb, wsrc, use_prep, x1c, yl, Tl, cl, x2l, A0, A1, A2);
    path_iter< 2>(tid, x1, z0, wb, wsrc, use_prep, x1c, yl, Tl, cl, x2l, A0, A1, A2);
    path_iter< 3>(tid, x1, z0, wb, wsrc, use_prep, x1c, yl, Tl, cl, x2l, A0, A1, A2);
    path_iter< 4>(tid, x1, z0, wb, wsrc, use_prep, x1c, yl, Tl, cl, x2l, A0, A1, A2);
    path_iter< 5>(tid, x1, z0, wb, wsrc, use_prep, x1c, yl, Tl, cl, x2l, A0, A1, A2);
    path_iter< 6>(tid, x1, z0, wb, wsrc, use_prep, x1c, yl, Tl, cl, x2l, A0, A1, A2);
    path_iter< 7>(tid, x1, z0, wb, wsrc, use_prep, x1c, yl, Tl, cl, x2l, A0, A1, A2);
    path_iter< 8>(tid, x1, z0, wb, wsrc, use_prep, x1c, yl, Tl, cl, x2l, A0, A1, A2);
    path_iter< 9>(tid, x1, z0, wb, wsrc, use_prep, x1c, yl, Tl, cl, x2l, A0, A1, A2);
    path_iter<10>(tid, x1, z0, wb, wsrc, use_prep, x1c, yl, Tl, cl, x2l, A0, A1, A2);
    path_iter<11>(tid, x1, z0, wb, wsrc, use_prep, x1c, yl, Tl, cl, x2l, A0, A1, A2);
    path_iter<12>(tid, x1, z0, wb, wsrc, use_prep, x1c, yl, Tl, cl, x2l, A0, A1, A2);
    path_iter<13>(tid, x1, z0, wb, wsrc, use_prep, x1c, yl, Tl, cl, x2l, A0, A1, A2);
    path_iter<14>(tid, x1, z0, wb, wsrc, use_prep, x1c, yl, Tl, cl, x2l, A0, A1, A2);

    // ---- coalesced epilogue: 4 chunks of 4 z, staged through LDS (reuses Tl) ----
    const int g = lane >> 4, m = lane & 15;
    float* stage = (float*)Tl;                 // 18.4 KB needed, 32.8 KB available
    #pragma unroll
    for (int c = 0; c < 4; ++c) {
        __syncthreads();                       // stage region free
        stage_lo<0, 1>(A0, stage, c, wv, g, m, 0.05103103630798288f);  // 1/sqrt(384)
        stage_lo<1, 3>(A1, stage, c, wv, g, m, 0.03608439182435161f);  // 1/sqrt(768)
        stage_lo<2, 5>(A2, stage, c, wv, g, m, 0.03608439182435161f);  // 1/sqrt(768)
        __syncthreads();                       // chunk staged
        float4* dst = (float4*)(out + (size_t)(z0 + 4*c) * 1152);
        const float4* src = (const float4*)stage;
        #pragma unroll
        for (int it = 0; it < 5; ++it) {
            const int idx = it * 256 + tid;    // float4 index, 1152 total
            if (idx < 1152) dst[idx] = src[idx];
        }
    }
}

extern "C" void kernel_launch(void* const* d_in, const int* in_sizes, int n_in,
                              void* d_out, int out_size, void* d_ws, size_t ws_size,
                              hipStream_t stream) {
    const float* x1 = (const float*)d_in[0];
    const float* x2 = (const float*)d_in[1];
    const float* ws = (const float*)d_in[2];
    CP cp;
    for (int p = 0; p < 15; ++p) cp.p[p] = (const float*)d_in[3 + p];
    float* out = (float*)d_out;

    const int N = in_sizes[0] / 1152;         // 16384
    const int use_prep = (ws_size >= (size_t)(15 * 128 * 128 * 2)) ? 1 : 0;

    if (use_prep)
        prep_w<<<15, 256, 0, stream>>>(ws, (ushort*)d_ws);
    tp_main<<<N / ZT, 256, 0, stream>>>(x1, x2, ws, (const ushort*)d_ws,
                                        use_prep, cp, out);
}

// Round 7
// 126.634 us; speedup vs baseline: 2.4578x; 2.4578x over previous
//
#include <hip/hip_runtime.h>
#include <hip/hip_bf16.h>

typedef float f32x4 __attribute__((ext_vector_type(4)));
typedef short bf16x8 __attribute__((ext_vector_type(8)));

#define ZT 16              // samples per workgroup
#define TL_RING 16384      // ring size in ushorts: 128 cols x 128 u (32.8 KB)
#define YL_BUF 640         // 16 z * max padded span (5k * 8i = 40)

// PATHS enumerated l1-major, l2, lo with |l1-l2|<=lo<=l1+l2
constexpr int cL1[15]  = {0,0,0,1,1,1,1,1,1,2,2,2,2,2,2};
constexpr int cL2[15]  = {0,1,2,0,1,1,1,2,2,0,1,1,2,2,2};
constexpr int cLO[15]  = {0,1,2,1,0,1,2,1,2,2,1,2,0,1,2};
constexpr int cCSZ[15] = {1,9,25,9,9,27,45,45,75,25,45,75,25,75,125};
constexpr int cCOFF[15]= {0,1,10,35,44,53,80,125,170,245,270,315,390,415,490}; // total 615
constexpr int cO1[3] = {0,128,512};  // x1 / out irrep block offsets (floats)
constexpr int cO2[3] = {0,1,4};      // x2 irrep block offsets

// Path sequence GROUPED BY l1 (x1 block regs reused within group; loaded at
// group starts S=0,3,9) + ring offsets (cols). Consecutive regions disjoint:
// [0,80)[80,128)[0,16)[48,128)[0,48)[112,128)[0,80)[80,128)[0,48)[48,128)
// [0,48)[48,128)[0,16)[80,128)[0,80).
constexpr int cSEQ [15] = {2,1,0, 6,3,4,8,5,7, 9,10,11,12,13,14};
constexpr int cROFF[15] = {0,80,0, 48,0,112,0,80,0, 48,0,48,0,80,0};

struct CP { const float* p[15]; };

__device__ __forceinline__ ushort f2bf(float f) {
    union { __hip_bfloat16 h; ushort u; } c;
    c.h = __float2bfloat16(f);
    return c.u;
}

// ---- prep kernel: Wb[p][w][u] = bf16(ws[p][u][0][w]) (transpose + convert) ----
__global__ void prep_w(const float* __restrict__ ws, ushort* __restrict__ wb) {
    __shared__ float lds[64 * 132];
    const int p = blockIdx.x;
    const int tid = threadIdx.x;
    const float* src = ws + (size_t)p * 16384;
    ushort* dst = wb + (size_t)p * 16384;
    for (int half = 0; half < 2; ++half) {
        for (int i = tid; i < 8192; i += 256) {          // load 64 u-rows, coalesced
            int u = i >> 7, w = i & 127;
            lds[u * 132 + w] = src[(half * 64 + u) * 128 + w];
        }
        __syncthreads();
        for (int i = tid; i < 8192; i += 256) {          // store transposed, coalesced
            int w = i >> 6, u = i & 63;
            dst[w * 128 + half * 64 + u] = f2bf(lds[u * 132 + w]);
        }
        __syncthreads();
    }
}

// ---- y in K-MAJOR layout: ybuf[z*span_pad + k*ipad + i] = sum_j c[i,j,k]*x2[z,j]
//      ipad = 8 if d1==5 else 4; pad slots zero. T-phase then loads 1-2 f32x4/k. ----
template<int P>
__device__ __forceinline__ void compute_y(int tid, const float* __restrict__ cl,
                                          const float* __restrict__ x2l,
                                          float* __restrict__ ybuf) {
    constexpr int l2 = cL2[P], lo = cLO[P];
    constexpr int d1 = 2*cL1[P]+1, d2 = 2*l2+1, dO = 2*lo+1;
    constexpr int ipad = (d1 == 5) ? 8 : 4;
    constexpr int span_pad = dO * ipad;
    constexpr int ny = ZT * span_pad;
    for (int idx = tid; idx < ny; idx += 256) {
        const int z = idx / span_pad, rem = idx - z * span_pad;
        const int k = rem / ipad, i = rem & (ipad - 1);
        float s = 0.f;
        if (i < d1) {
            #pragma unroll
            for (int j = 0; j < d2; ++j)
                s += cl[cCOFF[P] + (i*d2 + j)*dO + k] * x2l[z*9 + cO2[l2] + j];
        }
        ybuf[idx] = s;   // pad slots get 0; never consumed
    }
}

// ---- load current l1-block of x1 into regs (thread: u-pair 2*lane, z=4*wv+r) ----
template<int L1>
__device__ __forceinline__ void load_x1(const float* __restrict__ x1, int z0,
                                        int wv, int lane, float (&x1c)[4][2][5]) {
    #pragma unroll
    for (int r = 0; r < 4; ++r) {
        const float* b = x1 + (size_t)(z0 + wv*4 + r) * 1152;
        if constexpr (L1 == 0) {
            const float2 t = *reinterpret_cast<const float2*>(b + 2*lane);
            x1c[r][0][0] = t.x; x1c[r][1][0] = t.y;
        } else if constexpr (L1 == 1) {
            float f6[6];
            #pragma unroll
            for (int j = 0; j < 3; ++j) {
                const float2 t = *reinterpret_cast<const float2*>(b + 128 + 6*lane + 2*j);
                f6[2*j] = t.x; f6[2*j + 1] = t.y;
            }
            #pragma unroll
            for (int i = 0; i < 3; ++i) { x1c[r][0][i] = f6[i]; x1c[r][1][i] = f6[3+i]; }
        } else {
            float f10[10];
            #pragma unroll
            for (int j = 0; j < 5; ++j) {
                const float2 t = *reinterpret_cast<const float2*>(b + 512 + 10*lane + 2*j);
                f10[2*j] = t.x; f10[2*j + 1] = t.y;
            }
            #pragma unroll
            for (int i = 0; i < 5; ++i) { x1c[r][0][i] = f10[i]; x1c[r][1][i] = f10[5+i]; }
        }
    }
}

// ---- one sequence step: [x1 group load] -> T -> W-prefetch -> y(next) -> barrier -> MFMA ----
template<int S>
__device__ __forceinline__ void path_iter(
    int tid, const float* __restrict__ x1, int z0,
    const ushort* __restrict__ Wb, const float* __restrict__ Wsrc, int use_prep,
    float (&x1c)[4][2][5],
    float* __restrict__ yl, ushort* __restrict__ Tl,
    const float* __restrict__ cl, const float* __restrict__ x2l,
    f32x4 (&A0)[1][2], f32x4 (&A1)[3][2], f32x4 (&A2)[5][2])
{
    constexpr int P = cSEQ[S];
    constexpr int l1 = cL1[P], lo = cLO[P];
    constexpr int d1 = 2*l1+1, dO = 2*lo+1;
    constexpr int ipad = (d1 == 5) ? 8 : 4;
    constexpr int span_pad = dO * ipad;
    const int lane = tid & 63, wv = tid >> 6;

    ushort* Tcur = Tl + cROFF[S] * 128;             // ring region (cols x 128 u)
    const float* ycur = yl + (S & 1) * YL_BUF;

    // --- refresh x1 block registers at l1-group starts ---
    if constexpr (S == 0 || cL1[cSEQ[S - 1]] != l1)
        load_x1<l1>(x1, z0, wv, lane, x1c);

    // --- T-phase: thread owns u-pair (2*lane, 2*lane+1), z in {4*wv..4*wv+3}.
    //     y is k-major: per k load 1-2 f32x4 broadcasts (low reg footprint).
    //     Stride 128 ushorts + XOR swizzle (col&7)<<3 (write/read same involution) ---
    {
        const int u0 = 2 * lane;
        #pragma unroll
        for (int r = 0; r < 4; ++r) {
            const int z = wv * 4 + r;
            #pragma unroll
            for (int k = 0; k < dO; ++k) {
                const f32x4 y0 = *reinterpret_cast<const f32x4*>(
                    ycur + z * span_pad + k * ipad);
                float s0 = 0.f, s1 = 0.f;
                #pragma unroll
                for (int i = 0; i < ((d1 < 4) ? d1 : 4); ++i) {
                    s0 += x1c[r][0][i] * y0[i];
                    s1 += x1c[r][1][i] * y0[i];
                }
                if constexpr (d1 == 5) {
                    const float y4 = ycur[z * span_pad + k * ipad + 4];
                    s0 += x1c[r][0][4] * y4;
                    s1 += x1c[r][1][4] * y4;
                }
                const int col = z * dO + k;
                union { uint u32; ushort h[2]; } pk;
                pk.h[0] = f2bf(s0);
                pk.h[1] = f2bf(s1);
                const uint idx = (uint)(col * 128 + u0) ^ (uint)((col & 7) << 3);
                *reinterpret_cast<uint*>(Tcur + idx) = pk.u32;
            }
        }
    }

    // --- prefetch weight fragments (MFMA B-operand: k=u, col=w). After T-phase
    //     to keep peak live-set low; L2-resident, latency hides under y+barrier ---
    bf16x8 aP[2][4];
    if (use_prep) {
        const ushort* wp = Wb + P * 16384;
        #pragma unroll
        for (int nt = 0; nt < 2; ++nt)
        #pragma unroll
        for (int ks = 0; ks < 4; ++ks) {
            const int wrow = wv*32 + nt*16 + (lane & 15);
            const int k0   = ks*32 + ((lane >> 4) << 3);
            aP[nt][ks] = *reinterpret_cast<const bf16x8*>(wp + wrow*128 + k0);
        }
    } else {
        const float* wp = Wsrc + P * 16384;   // fallback: strided f32 reads of ws[p][u][0][w]
        #pragma unroll
        for (int nt = 0; nt < 2; ++nt)
        #pragma unroll
        for (int ks = 0; ks < 4; ++ks) {
            const int wrow = wv*32 + nt*16 + (lane & 15);
            const int k0   = ks*32 + ((lane >> 4) << 3);
            bf16x8 v;
            #pragma unroll
            for (int e = 0; e < 8; ++e) v[e] = (short)f2bf(wp[(k0 + e)*128 + wrow]);
            aP[nt][ks] = v;
        }
    }

    // --- overlap: compute next path's y into the other yl buffer ---
    if constexpr (S < 14)
        compute_y<cSEQ[S + 1]>(tid, cl, x2l, yl + ((S + 1) & 1) * YL_BUF);

    __syncthreads();   // T ready; ring adjacency guarantees no WAR with prev path

    // --- MFMA (swapped operands): D[w][zcol] with A=T (rows=zcol,k=u), B=W ---
    #pragma unroll
    for (int t = 0; t < dO; ++t) {
        #pragma unroll
        for (int ks = 0; ks < 4; ++ks) {
            const int col = t*16 + (lane & 15);
            const int k0  = ks*32 + ((lane >> 4) << 3);
            const uint idx = (uint)(col * 128 + k0) ^ (uint)((col & 7) << 3);
            const bf16x8 a = *reinterpret_cast<const bf16x8*>(Tcur + idx);
            if constexpr (lo == 0) {
                A0[t][0] = __builtin_amdgcn_mfma_f32_16x16x32_bf16(a, aP[0][ks], A0[t][0], 0,0,0);
                A0[t][1] = __builtin_amdgcn_mfma_f32_16x16x32_bf16(a, aP[1][ks], A0[t][1], 0,0,0);
            } else if constexpr (lo == 1) {
                A1[t][0] = __builtin_amdgcn_mfma_f32_16x16x32_bf16(a, aP[0][ks], A1[t][0], 0,0,0);
                A1[t][1] = __builtin_amdgcn_mfma_f32_16x16x32_bf16(a, aP[1][ks], A1[t][1], 0,0,0);
            } else {
                A2[t][0] = __builtin_amdgcn_mfma_f32_16x16x32_bf16(a, aP[0][ks], A2[t][0], 0,0,0);
                A2[t][1] = __builtin_amdgcn_mfma_f32_16x16x32_bf16(a, aP[1][ks], A2[t][1], 0,0,0);
            }
        }
    }
}

// ---- epilogue: stage acc (scaled) into LDS out-layout chunk of 4 z ----
// D layout: col(lane&15)->w, row((lane>>4)*4+r)->zcol. Stage write stride across
// the 16 m-lanes = dO -> 16 distinct banks -> conflict-free.
template<int LO, int NTILES>
__device__ __forceinline__ void stage_lo(const f32x4 (&A)[NTILES][2], float* __restrict__ stage,
                                         int c, int wv, int g, int m, float scale)
{
    constexpr int dO = 2*LO + 1;
    #pragma unroll
    for (int t = 0; t < NTILES; ++t)
    #pragma unroll
    for (int r = 0; r < 4; ++r) {
        const int zcol = t*16 + g*4 + r;
        const int z = zcol / dO, k = zcol - z*dO;
        if ((z >> 2) == c) {
            #pragma unroll
            for (int nt = 0; nt < 2; ++nt) {
                const int w = wv*32 + nt*16 + m;
                stage[(z & 3)*1152 + cO1[LO] + w*dO + k] = A[t][nt][r] * scale;
            }
        }
    }
}

__global__ __launch_bounds__(256, 2)
void tp_main(const float* __restrict__ x1, const float* __restrict__ x2,
             const float* __restrict__ wsrc, const ushort* __restrict__ wb,
             int use_prep, CP cp, float* __restrict__ out)
{
    __shared__ __align__(16) ushort Tl[TL_RING];      // 32.8 KB ring
    __shared__ __align__(16) float yl[2 * YL_BUF];    // 5.1 KB double-buffered y (k-major)
    __shared__ float cl[615];
    __shared__ float x2l[ZT * 9];

    const int tid = threadIdx.x;
    const int z0 = blockIdx.x * ZT;
    const int lane = tid & 63, wv = tid >> 6;

    // preload all CG tensors and the x2 tile
    #pragma unroll
    for (int p = 0; p < 15; ++p)
        for (int i = tid; i < cCSZ[p]; i += 256) cl[cCOFF[p] + i] = cp.p[p][i];
    for (int i = tid; i < ZT * 9; i += 256) x2l[i] = x2[(size_t)z0 * 9 + i];

    float x1c[4][2][5];   // current l1-group x1 block (<=40 regs), loaded per group

    f32x4 A0[1][2], A1[3][2], A2[5][2];
    #pragma unroll
    for (int nt = 0; nt < 2; ++nt) {
        A0[0][nt] = (f32x4){0.f, 0.f, 0.f, 0.f};
        #pragma unroll
        for (int t = 0; t < 3; ++t) A1[t][nt] = (f32x4){0.f, 0.f, 0.f, 0.f};
        #pragma unroll
        for (int t = 0; t < 5; ++t) A2[t][nt] = (f32x4){0.f, 0.f, 0.f, 0.f};
    }

    __syncthreads();                           // cl / x2l ready
    compute_y<cSEQ[0]>(tid, cl, x2l, yl);      // prime y for first path into yl[0]
    __syncthreads();                           // y ready

    path_iter< 0>(tid, x1, z0, wb, wsrc, use_prep, x1c, yl, Tl, cl, x2l, A0, A1, A2);
    path_iter< 1>(tid, x1, z0, wb, wsrc, use_prep, x1c, yl, Tl, cl, x2l, A0, A1, A2);
    path_iter< 2>(tid, x1, z0, wb, wsrc, use_prep, x1c, yl, Tl, cl, x2l, A0, A1, A2);
    path_iter< 3>(tid, x1, z0, wb, wsrc, use_prep, x1c, yl, Tl, cl, x2l, A0, A1, A2);
    path_iter< 4>(tid, x1, z0, wb, wsrc, use_prep, x1c, yl, Tl, cl, x2l, A0, A1, A2);
    path_iter< 5>(tid, x1, z0, wb, wsrc, use_prep, x1c, yl, Tl, cl, x2l, A0, A1, A2);
    path_iter< 6>(tid, x1, z0, wb, wsrc, use_prep, x1c, yl, Tl, cl, x2l, A0, A1, A2);
    path_iter< 7>(tid, x1, z0, wb, wsrc, use_prep, x1c, yl, Tl, cl, x2l, A0, A1, A2);
    path_iter< 8>(tid, x1, z0, wb, wsrc, use_prep, x1c, yl, Tl, cl, x2l, A0, A1, A2);
    path_iter< 9>(tid, x1, z0, wb, wsrc, use_prep, x1c, yl, Tl, cl, x2l, A0, A1, A2);
    path_iter<10>(tid, x1, z0, wb, wsrc, use_prep, x1c, yl, Tl, cl, x2l, A0, A1, A2);
    path_iter<11>(tid, x1, z0, wb, wsrc, use_prep, x1c, yl, Tl, cl, x2l, A0, A1, A2);
    path_iter<12>(tid, x1, z0, wb, wsrc, use_prep, x1c, yl, Tl, cl, x2l, A0, A1, A2);
    path_iter<13>(tid, x1, z0, wb, wsrc, use_prep, x1c, yl, Tl, cl, x2l, A0, A1, A2);
    path_iter<14>(tid, x1, z0, wb, wsrc, use_prep, x1c, yl, Tl, cl, x2l, A0, A1, A2);

    // ---- coalesced epilogue: 4 chunks of 4 z, staged through LDS (reuses Tl) ----
    const int g = lane >> 4, m = lane & 15;
    float* stage = (float*)Tl;                 // 18.4 KB needed, 32.8 KB available
    #pragma unroll
    for (int c = 0; c < 4; ++c) {
        __syncthreads();                       // stage region free
        stage_lo<0, 1>(A0, stage, c, wv, g, m, 0.05103103630798288f);  // 1/sqrt(384)
        stage_lo<1, 3>(A1, stage, c, wv, g, m, 0.03608439182435161f);  // 1/sqrt(768)
        stage_lo<2, 5>(A2, stage, c, wv, g, m, 0.03608439182435161f);  // 1/sqrt(768)
        __syncthreads();                       // chunk staged
        float4* dst = (float4*)(out + (size_t)(z0 + 4*c) * 1152);
        const float4* src = (const float4*)stage;
        #pragma unroll
        for (int it = 0; it < 5; ++it) {
            const int idx = it * 256 + tid;    // float4 index, 1152 total
            if (idx < 1152) dst[idx] = src[idx];
        }
    }
}

extern "C" void kernel_launch(void* const* d_in, const int* in_sizes, int n_in,
                              void* d_out, int out_size, void* d_ws, size_t ws_size,
                              hipStream_t stream) {
    const float* x1 = (const float*)d_in[0];
    const float* x2 = (const float*)d_in[1];
    const float* ws = (const float*)d_in[2];
    CP cp;
    for (int p = 0; p < 15; ++p) cp.p[p] = (const float*)d_in[3 + p];
    float* out = (float*)d_out;

    const int N = in_sizes[0] / 1152;         // 16384
    const int use_prep = (ws_size >= (size_t)(15 * 128 * 128 * 2)) ? 1 : 0;

    if (use_prep)
        prep_w<<<15, 256, 0, stream>>>(ws, (ushort*)d_ws);
    tp_main<<<N / ZT, 256, 0, stream>>>(x1, x2, ws, (const ushort*)d_ws,
                                        use_prep, cp, out);
}

// Round 8
// 106.129 us; speedup vs baseline: 2.9327x; 1.1932x over previous
//
#include <hip/hip_runtime.h>
#include <hip/hip_bf16.h>

typedef float f32x4 __attribute__((ext_vector_type(4)));
typedef short bf16x8 __attribute__((ext_vector_type(8)));

#define ZT 16              // samples per workgroup
#define TL_COLS 160        // ring: 160 cols x 128 u ushorts = 40960 B
#define TL_RING (TL_COLS * 128)
#define YL_BUF 640         // 16 z * max padded span (5k * 8i)

// PATHS enumerated l1-major, l2, lo with |l1-l2|<=lo<=l1+l2
constexpr int cL1[15]  = {0,0,0,1,1,1,1,1,1,2,2,2,2,2,2};
constexpr int cL2[15]  = {0,1,2,0,1,1,1,2,2,0,1,1,2,2,2};
constexpr int cLO[15]  = {0,1,2,1,0,1,2,1,2,2,1,2,0,1,2};
constexpr int cCSZ[15] = {1,9,25,9,9,27,45,45,75,25,45,75,25,75,125};
constexpr int cCOFF[15]= {0,1,10,35,44,53,80,125,170,245,270,315,390,415,490}; // total 615
constexpr int cO1[3] = {0,128,512};  // x1 / out irrep block offsets (floats)
constexpr int cO2[3] = {0,1,4};      // x2 irrep block offsets

// Path sequence grouped by OUTPUT lo (acc peak 40 regs, per-lo epilogue),
// sub-grouped by l1 (x1c reloads at 9 group starts). Ring region: S even->0,
// S odd->80 cols; region size 16*dO <= 80, consecutive disjoint.
constexpr int cSEQ[15] = {0,4,12, 1,3,5,7,10,13, 2,6,8,9,11,14};

struct CP { const float* p[15]; };

__device__ __forceinline__ ushort f2bf(float f) {
    union { __hip_bfloat16 h; ushort u; } c;
    c.h = __float2bfloat16(f);
    return c.u;
}

// ---- prep kernel: Wb[p][w][u] = bf16(ws[p][u][0][w]) (transpose + convert) ----
__global__ void prep_w(const float* __restrict__ ws, ushort* __restrict__ wb) {
    __shared__ float lds[64 * 132];
    const int p = blockIdx.x;
    const int tid = threadIdx.x;
    const float* src = ws + (size_t)p * 16384;
    ushort* dst = wb + (size_t)p * 16384;
    for (int half = 0; half < 2; ++half) {
        for (int i = tid; i < 8192; i += 256) {          // load 64 u-rows, coalesced
            int u = i >> 7, w = i & 127;
            lds[u * 132 + w] = src[(half * 64 + u) * 128 + w];
        }
        __syncthreads();
        for (int i = tid; i < 8192; i += 256) {          // store transposed, coalesced
            int w = i >> 6, u = i & 63;
            dst[w * 128 + half * 64 + u] = f2bf(lds[u * 132 + w]);
        }
        __syncthreads();
    }
}

// ---- y in K-MAJOR layout: ybuf[z*span_pad + k*ipad + i] = sum_j c[i,j,k]*x2[z,j] ----
template<int P>
__device__ __forceinline__ void compute_y(int tid, const float* __restrict__ cl,
                                          const float* __restrict__ x2l,
                                          float* __restrict__ ybuf) {
    constexpr int l2 = cL2[P], lo = cLO[P];
    constexpr int d1 = 2*cL1[P]+1, d2 = 2*l2+1, dO = 2*lo+1;
    constexpr int ipad = (d1 == 5) ? 8 : 4;
    constexpr int span_pad = dO * ipad;
    constexpr int ny = ZT * span_pad;
    for (int idx = tid; idx < ny; idx += 256) {
        const int z = idx / span_pad, rem = idx - z * span_pad;
        const int k = rem / ipad, i = rem & (ipad - 1);
        float s = 0.f;
        if (i < d1) {
            #pragma unroll
            for (int j = 0; j < d2; ++j)
                s += cl[cCOFF[P] + (i*d2 + j)*dO + k] * x2l[z*9 + cO2[l2] + j];
        }
        ybuf[idx] = s;   // pad slots get 0; never consumed
    }
}

// ---- load current l1-block of x1 into regs (thread: u-pair 2*lane, z=4*wv+r) ----
template<int L1>
__device__ __forceinline__ void load_x1(const float* __restrict__ x1, int z0,
                                        int wv, int lane, float (&x1c)[4][2][5]) {
    #pragma unroll
    for (int r = 0; r < 4; ++r) {
        const float* b = x1 + (size_t)(z0 + wv*4 + r) * 1152;
        if constexpr (L1 == 0) {
            const float2 t = *reinterpret_cast<const float2*>(b + 2*lane);
            x1c[r][0][0] = t.x; x1c[r][1][0] = t.y;
        } else if constexpr (L1 == 1) {
            float f6[6];
            #pragma unroll
            for (int j = 0; j < 3; ++j) {
                const float2 t = *reinterpret_cast<const float2*>(b + 128 + 6*lane + 2*j);
                f6[2*j] = t.x; f6[2*j + 1] = t.y;
            }
            #pragma unroll
            for (int i = 0; i < 3; ++i) { x1c[r][0][i] = f6[i]; x1c[r][1][i] = f6[3+i]; }
        } else {
            float f10[10];
            #pragma unroll
            for (int j = 0; j < 5; ++j) {
                const float2 t = *reinterpret_cast<const float2*>(b + 512 + 10*lane + 2*j);
                f10[2*j] = t.x; f10[2*j + 1] = t.y;
            }
            #pragma unroll
            for (int i = 0; i < 5; ++i) { x1c[r][0][i] = f10[i]; x1c[r][1][i] = f10[5+i]; }
        }
    }
}

// ---- one step: [x1 group load] -> T -> aP0 -> y(next) -> barrier -> MFMA(nt0) -> aP1 -> MFMA(nt1) ----
template<int S>
__device__ __forceinline__ void path_iter(
    int tid, const float* __restrict__ x1, int z0,
    const ushort* __restrict__ Wb, const float* __restrict__ Wsrc, int use_prep,
    float (&x1c)[4][2][5],
    float* __restrict__ yl, ushort* __restrict__ Tl,
    const float* __restrict__ cl, const float* __restrict__ x2l,
    f32x4 (&acc)[5][2])
{
    constexpr int P = cSEQ[S];
    constexpr int l1 = cL1[P], lo = cLO[P];
    constexpr int d1 = 2*l1+1, dO = 2*lo+1;
    constexpr int ipad = (d1 == 5) ? 8 : 4;
    constexpr int span_pad = dO * ipad;
    constexpr int roff = (S & 1) ? 80 : 0;
    const int lane = tid & 63, wv = tid >> 6;
    const int g = lane >> 4, m = lane & 15;

    ushort* Tcur = Tl + roff * 128;                 // ring region (cols x 128 u)
    const float* ycur = yl + (S & 1) * YL_BUF;

    // --- refresh x1 block registers at l1-group starts ---
    if constexpr (S == 0 || cL1[cSEQ[S - 1]] != l1)
        load_x1<l1>(x1, z0, wv, lane, x1c);

    // --- T-phase: thread owns u-pair (2*lane, 2*lane+1), z in {4*wv..4*wv+3}.
    //     y is k-major; stride-128 + XOR swizzle (col&7)<<3, write/read same involution ---
    {
        const int u0 = 2 * lane;
        #pragma unroll
        for (int r = 0; r < 4; ++r) {
            const int z = wv * 4 + r;
            #pragma unroll
            for (int k = 0; k < dO; ++k) {
                const f32x4 y0 = *reinterpret_cast<const f32x4*>(
                    ycur + z * span_pad + k * ipad);
                float s0 = 0.f, s1 = 0.f;
                #pragma unroll
                for (int i = 0; i < ((d1 < 4) ? d1 : 4); ++i) {
                    s0 += x1c[r][0][i] * y0[i];
                    s1 += x1c[r][1][i] * y0[i];
                }
                if constexpr (d1 == 5) {
                    const float y4 = ycur[z * span_pad + k * ipad + 4];
                    s0 += x1c[r][0][4] * y4;
                    s1 += x1c[r][1][4] * y4;
                }
                const int col = z * dO + k;
                union { uint u32; ushort h[2]; } pk;
                pk.h[0] = f2bf(s0);
                pk.h[1] = f2bf(s1);
                const uint idx = (uint)(col * 128 + u0) ^ (uint)((col & 7) << 3);
                *reinterpret_cast<uint*>(Tcur + idx) = pk.u32;
            }
        }
    }

    // --- prefetch nt=0 weight fragments only (16 regs; aP1 loaded later) ---
    bf16x8 aP0[4];
    if (use_prep) {
        const ushort* wp = Wb + P * 16384;
        #pragma unroll
        for (int ks = 0; ks < 4; ++ks)
            aP0[ks] = *reinterpret_cast<const bf16x8*>(wp + (wv*32 + m)*128 + ks*32 + g*8);
    } else {
        const float* wp = Wsrc + P * 16384;
        #pragma unroll
        for (int ks = 0; ks < 4; ++ks) {
            bf16x8 v;
            #pragma unroll
            for (int e = 0; e < 8; ++e) v[e] = (short)f2bf(wp[(ks*32 + g*8 + e)*128 + wv*32 + m]);
            aP0[ks] = v;
        }
    }

    // --- overlap: compute next path's y into the other yl buffer ---
    if constexpr (S < 14)
        compute_y<cSEQ[S + 1]>(tid, cl, x2l, yl + ((S + 1) & 1) * YL_BUF);

    __syncthreads();   // T ready; ring adjacency guarantees no WAR with prev path

    // --- MFMA half-pass nt=0: D[w][zcol], A=T (rows=zcol,k=u), B=W ---
    #pragma unroll
    for (int t = 0; t < dO; ++t) {
        #pragma unroll
        for (int ks = 0; ks < 4; ++ks) {
            const uint idx = (uint)((t*16 + m) * 128 + ks*32 + g*8)
                           ^ (uint)(((t*16 + m) & 7) << 3);
            const bf16x8 a = *reinterpret_cast<const bf16x8*>(Tcur + idx);
            acc[t][0] = __builtin_amdgcn_mfma_f32_16x16x32_bf16(a, aP0[ks], acc[t][0], 0,0,0);
        }
    }

    // --- nt=1 fragments (reuses the 16-reg slot; aP0 dead) ---
    bf16x8 aP1[4];
    if (use_prep) {
        const ushort* wp = Wb + P * 16384;
        #pragma unroll
        for (int ks = 0; ks < 4; ++ks)
            aP1[ks] = *reinterpret_cast<const bf16x8*>(wp + (wv*32 + 16 + m)*128 + ks*32 + g*8);
    } else {
        const float* wp = Wsrc + P * 16384;
        #pragma unroll
        for (int ks = 0; ks < 4; ++ks) {
            bf16x8 v;
            #pragma unroll
            for (int e = 0; e < 8; ++e) v[e] = (short)f2bf(wp[(ks*32 + g*8 + e)*128 + wv*32 + 16 + m]);
            aP1[ks] = v;
        }
    }

    // --- MFMA half-pass nt=1 (A-frags re-read; trades LDS reads for 16 regs) ---
    #pragma unroll
    for (int t = 0; t < dO; ++t) {
        #pragma unroll
        for (int ks = 0; ks < 4; ++ks) {
            const uint idx = (uint)((t*16 + m) * 128 + ks*32 + g*8)
                           ^ (uint)(((t*16 + m) & 7) << 3);
            const bf16x8 a = *reinterpret_cast<const bf16x8*>(Tcur + idx);
            acc[t][1] = __builtin_amdgcn_mfma_f32_16x16x32_bf16(a, aP1[ks], acc[t][1], 0,0,0);
        }
    }
}

// ---- per-lo epilogue: stage full lo-block (16 z) in ring, then coalesced f4 store ----
template<int LO, bool LAST>
__device__ __forceinline__ void store_pass(const f32x4 (&acc)[5][2], float* __restrict__ out,
                                           float* __restrict__ stage, int z0, int tid)
{
    constexpr int dO = 2*LO + 1;
    constexpr float scale = (LO == 0) ? 0.05103103630798288f    // 1/sqrt(384)
                                      : 0.03608439182435161f;   // 1/sqrt(768)
    const int lane = tid & 63, wv = tid >> 6;
    const int g = lane >> 4, m = lane & 15;
    __syncthreads();                        // ring free (all MFMA reads done)
    #pragma unroll
    for (int t = 0; t < dO; ++t)
    #pragma unroll
    for (int r = 0; r < 4; ++r) {
        const int zcol = t*16 + g*4 + r;
        const int z = zcol / dO, k = zcol - z*dO;
        #pragma unroll
        for (int nt = 0; nt < 2; ++nt) {
            const int w = wv*32 + nt*16 + m;
            stage[z*(128*dO) + w*dO + k] = acc[t][nt][r] * scale;  // stride dO over m: conflict-free
        }
    }
    __syncthreads();                        // staged
    const float4* src = (const float4*)stage;
    #pragma unroll
    for (int it = 0; it < 2*dO; ++it) {
        const int idx = it * 256 + tid;     // [0, 512*dO)
        const int z = idx / (32*dO), rem = idx - z*(32*dO);
        ((float4*)(out + (size_t)(z0 + z)*1152 + cO1[LO]))[rem] = src[idx];
    }
    if constexpr (!LAST) __syncthreads();   // store-reads done before ring reuse
}

__device__ __forceinline__ void zero_acc(f32x4 (&acc)[5][2]) {
    #pragma unroll
    for (int t = 0; t < 5; ++t)
        #pragma unroll
        for (int nt = 0; nt < 2; ++nt)
            acc[t][nt] = (f32x4){0.f, 0.f, 0.f, 0.f};
}

__global__ __launch_bounds__(256, 2)
void tp_main(const float* __restrict__ x1, const float* __restrict__ x2,
             const float* __restrict__ wsrc, const ushort* __restrict__ wb,
             int use_prep, CP cp, float* __restrict__ out)
{
    __shared__ __align__(16) ushort Tl[TL_RING];      // 40.96 KB ring / epilogue stage
    __shared__ __align__(16) float yl[2 * YL_BUF];    // 5.1 KB double-buffered y (k-major)
    __shared__ float cl[615];
    __shared__ float x2l[ZT * 9];

    const int tid = threadIdx.x;
    const int z0 = blockIdx.x * ZT;

    // preload all CG tensors and the x2 tile
    #pragma unroll
    for (int p = 0; p < 15; ++p)
        for (int i = tid; i < cCSZ[p]; i += 256) cl[cCOFF[p] + i] = cp.p[p][i];
    for (int i = tid; i < ZT * 9; i += 256) x2l[i] = x2[(size_t)z0 * 9 + i];

    float x1c[4][2][5];   // current l1-group x1 block (<=40 regs)
    f32x4 acc[5][2];      // current lo-pass accumulator (<=40 regs)
    zero_acc(acc);

    __syncthreads();                           // cl / x2l ready
    compute_y<cSEQ[0]>(tid, cl, x2l, yl);      // prime y for first path into yl[0]
    __syncthreads();                           // y ready

    float* stage = (float*)Tl;

    // ---- lo = 0 pass (3 paths) ----
    path_iter< 0>(tid, x1, z0, wb, wsrc, use_prep, x1c, yl, Tl, cl, x2l, acc);
    path_iter< 1>(tid, x1, z0, wb, wsrc, use_prep, x1c, yl, Tl, cl, x2l, acc);
    path_iter< 2>(tid, x1, z0, wb, wsrc, use_prep, x1c, yl, Tl, cl, x2l, acc);
    store_pass<0, false>(acc, out, stage, z0, tid);
    zero_acc(acc);

    // ---- lo = 1 pass (6 paths) ----
    path_iter< 3>(tid, x1, z0, wb, wsrc, use_prep, x1c, yl, Tl, cl, x2l, acc);
    path_iter< 4>(tid, x1, z0, wb, wsrc, use_prep, x1c, yl, Tl, cl, x2l, acc);
    path_iter< 5>(tid, x1, z0, wb, wsrc, use_prep, x1c, yl, Tl, cl, x2l, acc);
    path_iter< 6>(tid, x1, z0, wb, wsrc, use_prep, x1c, yl, Tl, cl, x2l, acc);
    path_iter< 7>(tid, x1, z0, wb, wsrc, use_prep, x1c, yl, Tl, cl, x2l, acc);
    path_iter< 8>(tid, x1, z0, wb, wsrc, use_prep, x1c, yl, Tl, cl, x2l, acc);
    store_pass<1, false>(acc, out, stage, z0, tid);
    zero_acc(acc);

    // ---- lo = 2 pass (6 paths) ----
    path_iter< 9>(tid, x1, z0, wb, wsrc, use_prep, x1c, yl, Tl, cl, x2l, acc);
    path_iter<10>(tid, x1, z0, wb, wsrc, use_prep, x1c, yl, Tl, cl, x2l, acc);
    path_iter<11>(tid, x1, z0, wb, wsrc, use_prep, x1c, yl, Tl, cl, x2l, acc);
    path_iter<12>(tid, x1, z0, wb, wsrc, use_prep, x1c, yl, Tl, cl, x2l, acc);
    path_iter<13>(tid, x1, z0, wb, wsrc, use_prep, x1c, yl, Tl, cl, x2l, acc);
    path_iter<14>(tid, x1, z0, wb, wsrc, use_prep, x1c, yl, Tl, cl, x2l, acc);
    store_pass<2, true>(acc, out, stage, z0, tid);
}

extern "C" void kernel_launch(void* const* d_in, const int* in_sizes, int n_in,
                              void* d_out, int out_size, void* d_ws, size_t ws_size,
                              hipStream_t stream) {
    const float* x1 = (const float*)d_in[0];
    const float* x2 = (const float*)d_in[1];
    const float* ws = (const float*)d_in[2];
    CP cp;
    for (int p = 0; p < 15; ++p) cp.p[p] = (const float*)d_in[3 + p];
    float* out = (float*)d_out;

    const int N = in_sizes[0] / 1152;         // 16384
    const int use_prep = (ws_size >= (size_t)(15 * 128 * 128 * 2)) ? 1 : 0;

    if (use_prep)
        prep_w<<<15, 256, 0, stream>>>(ws, (ushort*)d_ws);
    tp_main<<<N / ZT, 256, 0, stream>>>(x1, x2, ws, (const ushort*)d_ws,
                                        use_prep, cp, out);
}

// Round 10
// 104.937 us; speedup vs baseline: 2.9660x; 1.0114x over previous
//
#include <hip/hip_runtime.h>
#include <hip/hip_bf16.h>

typedef float f32x4 __attribute__((ext_vector_type(4)));
typedef short bf16x8 __attribute__((ext_vector_type(8)));

#define ZT 16              // samples per workgroup
#define TL_COLS 160        // ring: 160 cols x 128 u ushorts = 40960 B
#define TL_RING (TL_COLS * 128)
#define YL_BUF 640         // 16 z * max padded span (5k * 8i)

// PATHS enumerated l1-major, l2, lo with |l1-l2|<=lo<=l1+l2
constexpr int cL1[15]  = {0,0,0,1,1,1,1,1,1,2,2,2,2,2,2};
constexpr int cL2[15]  = {0,1,2,0,1,1,1,2,2,0,1,1,2,2,2};
constexpr int cLO[15]  = {0,1,2,1,0,1,2,1,2,2,1,2,0,1,2};
constexpr int cCSZ[15] = {1,9,25,9,9,27,45,45,75,25,45,75,25,75,125};
constexpr int cCOFF[15]= {0,1,10,35,44,53,80,125,170,245,270,315,390,415,490}; // total 615
constexpr int cO1[3] = {0,128,512};  // x1 / out irrep block offsets (floats)
constexpr int cO2[3] = {0,1,4};      // x2 irrep block offsets

// Path sequence grouped by OUTPUT lo (acc peak 40 regs, per-lo epilogue),
// sub-grouped by l1 (x1c reloads at 9 group starts). Ring region: S even->0,
// S odd->80 cols; region size 16*dO <= 80, consecutive disjoint.
constexpr int cSEQ[15] = {0,4,12, 1,3,5,7,10,13, 2,6,8,9,11,14};

struct CP { const float* p[15]; };

__device__ __forceinline__ ushort f2bf(float f) {
    union { __hip_bfloat16 h; ushort u; } c;
    c.h = __float2bfloat16(f);
    return c.u;
}

// ---- prep kernel: Wb[p][w][u] = bf16(ws[p][u][0][w]) (transpose + convert) ----
__global__ void prep_w(const float* __restrict__ ws, ushort* __restrict__ wb) {
    __shared__ float lds[64 * 132];
    const int p = blockIdx.x;
    const int tid = threadIdx.x;
    const float* src = ws + (size_t)p * 16384;
    ushort* dst = wb + (size_t)p * 16384;
    for (int half = 0; half < 2; ++half) {
        for (int i = tid; i < 8192; i += 256) {          // load 64 u-rows, coalesced
            int u = i >> 7, w = i & 127;
            lds[u * 132 + w] = src[(half * 64 + u) * 128 + w];
        }
        __syncthreads();
        for (int i = tid; i < 8192; i += 256) {          // store transposed, coalesced
            int w = i >> 6, u = i & 63;
            dst[w * 128 + half * 64 + u] = f2bf(lds[u * 132 + w]);
        }
        __syncthreads();
    }
}

// ---- y in K-MAJOR layout: ybuf[z*span_pad + k*ipad + i] = sum_j c[i,j,k]*x2[z,j] ----
template<int P>
__device__ __forceinline__ void compute_y(int tid, const float* __restrict__ cl,
                                          const float* __restrict__ x2l,
                                          float* __restrict__ ybuf) {
    constexpr int l2 = cL2[P], lo = cLO[P];
    constexpr int d1 = 2*cL1[P]+1, d2 = 2*l2+1, dO = 2*lo+1;
    constexpr int ipad = (d1 == 5) ? 8 : 4;
    constexpr int span_pad = dO * ipad;
    constexpr int ny = ZT * span_pad;
    for (int idx = tid; idx < ny; idx += 256) {
        const int z = idx / span_pad, rem = idx - z * span_pad;
        const int k = rem / ipad, i = rem & (ipad - 1);
        float s = 0.f;
        if (i < d1) {
            #pragma unroll
            for (int j = 0; j < d2; ++j)
                s += cl[cCOFF[P] + (i*d2 + j)*dO + k] * x2l[z*9 + cO2[l2] + j];
        }
        ybuf[idx] = s;   // pad slots get 0; never consumed
    }
}

// ---- load current l1-block of x1 into regs (thread: u-pair 2*lane, z=4*wv+r) ----
template<int L1>
__device__ __forceinline__ void load_x1(const float* __restrict__ x1, int z0,
                                        int wv, int lane, float (&x1c)[4][2][5]) {
    #pragma unroll
    for (int r = 0; r < 4; ++r) {
        const float* b = x1 + (size_t)(z0 + wv*4 + r) * 1152;
        if constexpr (L1 == 0) {
            const float2 t = *reinterpret_cast<const float2*>(b + 2*lane);
            x1c[r][0][0] = t.x; x1c[r][1][0] = t.y;
        } else if constexpr (L1 == 1) {
            float f6[6];
            #pragma unroll
            for (int j = 0; j < 3; ++j) {
                const float2 t = *reinterpret_cast<const float2*>(b + 128 + 6*lane + 2*j);
                f6[2*j] = t.x; f6[2*j + 1] = t.y;
            }
            #pragma unroll
            for (int i = 0; i < 3; ++i) { x1c[r][0][i] = f6[i]; x1c[r][1][i] = f6[3+i]; }
        } else {
            float f10[10];
            #pragma unroll
            for (int j = 0; j < 5; ++j) {
                const float2 t = *reinterpret_cast<const float2*>(b + 512 + 10*lane + 2*j);
                f10[2*j] = t.x; f10[2*j + 1] = t.y;
            }
            #pragma unroll
            for (int i = 0; i < 5; ++i) { x1c[r][0][i] = f10[i]; x1c[r][1][i] = f10[5+i]; }
        }
    }
}

// ---- one step: [x1 group load] -> T -> aP[2][4] -> y(next) -> barrier -> MFMA ----
template<int S>
__device__ __forceinline__ void path_iter(
    int tid, const float* __restrict__ x1, int z0,
    const ushort* __restrict__ Wb, const float* __restrict__ Wsrc, int use_prep,
    float (&x1c)[4][2][5],
    float* __restrict__ yl, ushort* __restrict__ Tl,
    const float* __restrict__ cl, const float* __restrict__ x2l,
    f32x4 (&acc)[5][2])
{
    constexpr int P = cSEQ[S];
    constexpr int l1 = cL1[P], lo = cLO[P];
    constexpr int d1 = 2*l1+1, dO = 2*lo+1;
    constexpr int ipad = (d1 == 5) ? 8 : 4;
    constexpr int span_pad = dO * ipad;
    constexpr int roff = (S & 1) ? 80 : 0;
    const int lane = tid & 63, wv = tid >> 6;
    const int g = lane >> 4, m = lane & 15;

    ushort* Tcur = Tl + roff * 128;                 // ring region (cols x 128 u)
    const float* ycur = yl + (S & 1) * YL_BUF;

    // --- refresh x1 block registers at l1-group starts ---
    if constexpr (S == 0 || cL1[cSEQ[S - 1]] != l1)
        load_x1<l1>(x1, z0, wv, lane, x1c);

    // --- T-phase: thread owns u-pair (2*lane, 2*lane+1), z in {4*wv..4*wv+3}.
    //     y is k-major; stride-128 + XOR swizzle (col&7)<<3, write/read same involution ---
    {
        const int u0 = 2 * lane;
        #pragma unroll
        for (int r = 0; r < 4; ++r) {
            const int z = wv * 4 + r;
            #pragma unroll
            for (int k = 0; k < dO; ++k) {
                const f32x4 y0 = *reinterpret_cast<const f32x4*>(
                    ycur + z * span_pad + k * ipad);
                float s0 = 0.f, s1 = 0.f;
                #pragma unroll
                for (int i = 0; i < ((d1 < 4) ? d1 : 4); ++i) {
                    s0 += x1c[r][0][i] * y0[i];
                    s1 += x1c[r][1][i] * y0[i];
                }
                if constexpr (d1 == 5) {
                    const float y4 = ycur[z * span_pad + k * ipad + 4];
                    s0 += x1c[r][0][4] * y4;
                    s1 += x1c[r][1][4] * y4;
                }
                const int col = z * dO + k;
                union { uint u32; ushort h[2]; } pk;
                pk.h[0] = f2bf(s0);
                pk.h[1] = f2bf(s1);
                const uint idx = (uint)(col * 128 + u0) ^ (uint)((col & 7) << 3);
                *reinterpret_cast<uint*>(Tcur + idx) = pk.u32;
            }
        }
    }

    // --- prefetch both weight fragment sets (MFMA B-operand: k=u, col=w) ---
    bf16x8 aP[2][4];
    if (use_prep) {
        const ushort* wp = Wb + P * 16384;
        #pragma unroll
        for (int nt = 0; nt < 2; ++nt)
        #pragma unroll
        for (int ks = 0; ks < 4; ++ks)
            aP[nt][ks] = *reinterpret_cast<const bf16x8*>(
                wp + (wv*32 + nt*16 + m)*128 + ks*32 + g*8);
    } else {
        const float* wp = Wsrc + P * 16384;
        #pragma unroll
        for (int nt = 0; nt < 2; ++nt)
        #pragma unroll
        for (int ks = 0; ks < 4; ++ks) {
            bf16x8 v;
            #pragma unroll
            for (int e = 0; e < 8; ++e)
                v[e] = (short)f2bf(wp[(ks*32 + g*8 + e)*128 + wv*32 + nt*16 + m]);
            aP[nt][ks] = v;
        }
    }

    // --- overlap: compute next path's y into the other yl buffer ---
    if constexpr (S < 14)
        compute_y<cSEQ[S + 1]>(tid, cl, x2l, yl + ((S + 1) & 1) * YL_BUF);

    __syncthreads();   // T ready; ring adjacency guarantees no WAR with prev path

    // --- MFMA: read each A-fragment ONCE, feed both nt MFMAs ---
    #pragma unroll
    for (int t = 0; t < dO; ++t) {
        #pragma unroll
        for (int ks = 0; ks < 4; ++ks) {
            const uint idx = (uint)((t*16 + m) * 128 + ks*32 + g*8)
                           ^ (uint)(((t*16 + m) & 7) << 3);
            const bf16x8 a = *reinterpret_cast<const bf16x8*>(Tcur + idx);
            acc[t][0] = __builtin_amdgcn_mfma_f32_16x16x32_bf16(a, aP[0][ks], acc[t][0], 0,0,0);
            acc[t][1] = __builtin_amdgcn_mfma_f32_16x16x32_bf16(a, aP[1][ks], acc[t][1], 0,0,0);
        }
    }
}

// ---- per-lo epilogue: stage full lo-block (16 z) in ring, then coalesced f4 store ----
template<int LO, bool LAST>
__device__ __forceinline__ void store_pass(const f32x4 (&acc)[5][2], float* __restrict__ out,
                                           float* __restrict__ stage, int z0, int tid)
{
    constexpr int dO = 2*LO + 1;
    constexpr float scale = (LO == 0) ? 0.05103103630798288f    // 1/sqrt(384)
                                      : 0.03608439182435161f;   // 1/sqrt(768)
    const int lane = tid & 63, wv = tid >> 6;
    const int g = lane >> 4, m = lane & 15;
    __syncthreads();                        // ring free (all MFMA reads done)
    #pragma unroll
    for (int t = 0; t < dO; ++t)
    #pragma unroll
    for (int r = 0; r < 4; ++r) {
        const int zcol = t*16 + g*4 + r;
        const int z = zcol / dO, k = zcol - z*dO;
        #pragma unroll
        for (int nt = 0; nt < 2; ++nt) {
            const int w = wv*32 + nt*16 + m;
            stage[z*(128*dO) + w*dO + k] = acc[t][nt][r] * scale;  // stride dO over m: conflict-free
        }
    }
    __syncthreads();                        // staged
    const float4* src = (const float4*)stage;
    #pragma unroll
    for (int it = 0; it < 2*dO; ++it) {
        const int idx = it * 256 + tid;     // [0, 512*dO)
        const int z = idx / (32*dO), rem = idx - z*(32*dO);
        ((float4*)(out + (size_t)(z0 + z)*1152 + cO1[LO]))[rem] = src[idx];
    }
    if constexpr (!LAST) __syncthreads();   // store-reads done before ring reuse
}

__device__ __forceinline__ void zero_acc(f32x4 (&acc)[5][2]) {
    #pragma unroll
    for (int t = 0; t < 5; ++t)
        #pragma unroll
        for (int nt = 0; nt < 2; ++nt)
            acc[t][nt] = (f32x4){0.f, 0.f, 0.f, 0.f};
}

__global__ __launch_bounds__(256, 2)
void tp_main(const float* __restrict__ x1, const float* __restrict__ x2,
             const float* __restrict__ wsrc, const ushort* __restrict__ wb,
             int use_prep, CP cp, float* __restrict__ out)
{
    __shared__ __align__(16) ushort Tl[TL_RING];      // 40.96 KB ring / epilogue stage
    __shared__ __align__(16) float yl[2 * YL_BUF];    // 5.1 KB double-buffered y (k-major)
    __shared__ float cl[615];
    __shared__ float x2l[ZT * 9];

    const int tid = threadIdx.x;
    const int z0 = blockIdx.x * ZT;

    // preload all CG tensors and the x2 tile
    #pragma unroll
    for (int p = 0; p < 15; ++p)
        for (int i = tid; i < cCSZ[p]; i += 256) cl[cCOFF[p] + i] = cp.p[p][i];
    for (int i = tid; i < ZT * 9; i += 256) x2l[i] = x2[(size_t)z0 * 9 + i];

    float x1c[4][2][5];   // current l1-group x1 block (<=40 regs)
    f32x4 acc[5][2];      // current lo-pass accumulator (<=40 regs)
    zero_acc(acc);

    __syncthreads();                           // cl / x2l ready
    compute_y<cSEQ[0]>(tid, cl, x2l, yl);      // prime y for first path into yl[0]
    __syncthreads();                           // y ready

    float* stage = (float*)Tl;

    // ---- lo = 0 pass (3 paths) ----
    path_iter< 0>(tid, x1, z0, wb, wsrc, use_prep, x1c, yl, Tl, cl, x2l, acc);
    path_iter< 1>(tid, x1, z0, wb, wsrc, use_prep, x1c, yl, Tl, cl, x2l, acc);
    path_iter< 2>(tid, x1, z0, wb, wsrc, use_prep, x1c, yl, Tl, cl, x2l, acc);
    store_pass<0, false>(acc, out, stage, z0, tid);
    zero_acc(acc);

    // ---- lo = 1 pass (6 paths) ----
    path_iter< 3>(tid, x1, z0, wb, wsrc, use_prep, x1c, yl, Tl, cl, x2l, acc);
    path_iter< 4>(tid, x1, z0, wb, wsrc, use_prep, x1c, yl, Tl, cl, x2l, acc);
    path_iter< 5>(tid, x1, z0, wb, wsrc, use_prep, x1c, yl, Tl, cl, x2l, acc);
    path_iter< 6>(tid, x1, z0, wb, wsrc, use_prep, x1c, yl, Tl, cl, x2l, acc);
    path_iter< 7>(tid, x1, z0, wb, wsrc, use_prep, x1c, yl, Tl, cl, x2l, acc);
    path_iter< 8>(tid, x1, z0, wb, wsrc, use_prep, x1c, yl, Tl, cl, x2l, acc);
    store_pass<1, false>(acc, out, stage, z0, tid);
    zero_acc(acc);

    // ---- lo = 2 pass (6 paths) ----
    path_iter< 9>(tid, x1, z0, wb, wsrc, use_prep, x1c, yl, Tl, cl, x2l, acc);
    path_iter<10>(tid, x1, z0, wb, wsrc, use_prep, x1c, yl, Tl, cl, x2l, acc);
    path_iter<11>(tid, x1, z0, wb, wsrc, use_prep, x1c, yl, Tl, cl, x2l, acc);
    path_iter<12>(tid, x1, z0, wb, wsrc, use_prep, x1c, yl, Tl, cl, x2l, acc);
    path_iter<13>(tid, x1, z0, wb, wsrc, use_prep, x1c, yl, Tl, cl, x2l, acc);
    path_iter<14>(tid, x1, z0, wb, wsrc, use_prep, x1c, yl, Tl, cl, x2l, acc);
    store_pass<2, true>(acc, out, stage, z0, tid);
}

extern "C" void kernel_launch(void* const* d_in, const int* in_sizes, int n_in,
                              void* d_out, int out_size, void* d_ws, size_t ws_size,
                              hipStream_t stream) {
    const float* x1 = (const float*)d_in[0];
    const float* x2 = (const float*)d_in[1];
    const float* ws = (const float*)d_in[2];
    CP cp;
    for (int p = 0; p < 15; ++p) cp.p[p] = (const float*)d_in[3 + p];
    float* out = (float*)d_out;

    const int N = in_sizes[0] / 1152;         // 16384
    const int use_prep = (ws_size >= (size_t)(15 * 128 * 128 * 2)) ? 1 : 0;

    if (use_prep)
        prep_w<<<15, 256, 0, stream>>>(ws, (ushort*)d_ws);
    tp_main<<<N / ZT, 256, 0, stream>>>(x1, x2, ws, (const ushort*)d_ws,
                                        use_prep, cp, out);
}